// Round 1
// baseline (2130.734 us; speedup 1.0000x reference)
//
#include <hip/hip_runtime.h>
#include <math.h>

#define SQ 4096
#define DM 1024
#define NB 4
#define MT (NB*SQ)   // 16384 flattened rows

typedef __attribute__((ext_vector_type(4))) float f32x4;
typedef __attribute__((ext_vector_type(8))) short s16x8;

__device__ __forceinline__ unsigned short f2bf(float f) {
  union { float f; unsigned int u; } v; v.f = f;
  unsigned int u = v.u;
  u += 0x7fffu + ((u >> 16) & 1u);   // RNE
  return (unsigned short)(u >> 16);
}

__device__ __forceinline__ void async16(const void* g, void* l) {
  __builtin_amdgcn_global_load_lds(
      (const __attribute__((address_space(1))) unsigned int*)g,
      (__attribute__((address_space(3))) unsigned int*)l, 16, 0, 0);
}

// ---------------- fp32 -> bf16 convert ----------------
__global__ __launch_bounds__(256)
void cvt(const float* __restrict__ in, unsigned short* __restrict__ out) {
  size_t i = ((size_t)blockIdx.x * 256 + threadIdx.x) * 4;
  float4 f = *(const float4*)(in + i);
  ushort4 o;
  o.x = f2bf(f.x); o.y = f2bf(f.y); o.z = f2bf(f.z); o.w = f2bf(f.w);
  *(ushort4*)(out + i) = o;
}

// ---------------- GEMM C = A * B^T (bf16 in, bf16 out), optional fused RoPE ----------------
// A: [MT][1024] bf16, Bw: [1024][1024] bf16 (row = out dim), C: [MT][1024] bf16
// 128x128 tile, BK=64, 4 waves each 64x64, 16x16x32 MFMA, global_load_lds + XOR swizzle.
template<int ROPE>
__global__ __launch_bounds__(256)
void gemm_rope(const unsigned short* __restrict__ A,
               const unsigned short* __restrict__ Bw,
               unsigned short* __restrict__ C) {
  __shared__ unsigned short As[128 * 64];
  __shared__ unsigned short Bs[128 * 64];
  const int tid = threadIdx.x, lane = tid & 63, wid = tid >> 6;
  const int quad = lane >> 4, l15 = lane & 15;
  const int wm = wid & 1, wn = wid >> 1;
  const int m0 = blockIdx.x * 128, n0 = blockIdx.y * 128;

  f32x4 zero = {0.f, 0.f, 0.f, 0.f};
  f32x4 acc[4][4];
#pragma unroll
  for (int i = 0; i < 4; i++)
#pragma unroll
    for (int j = 0; j < 4; j++) acc[i][j] = zero;

  for (int k0 = 0; k0 < DM; k0 += 64) {
    // stage A,B tiles: slot s holds row r=s>>3, phys 16B-group cg=s&7 = (logical kg) ^ (r&7)
#pragma unroll
    for (int c = 0; c < 4; c++) {
      int slot = (wid * 4 + c) * 64 + lane;
      int r = slot >> 3;
      int kg = (slot & 7) ^ (r & 7);
      async16(A  + (size_t)(m0 + r) * DM + k0 + kg * 8, As + slot * 8);
      async16(Bw + (size_t)(n0 + r) * DM + k0 + kg * 8, Bs + slot * 8);
    }
    asm volatile("s_waitcnt vmcnt(0)" ::: "memory");
    __syncthreads();
#pragma unroll
    for (int ks = 0; ks < 2; ks++) {
      s16x8 af[4], bfr[4];
#pragma unroll
      for (int t = 0; t < 4; t++) {
        int mr = wm * 64 + t * 16 + l15;
        af[t]  = *(const s16x8*)(As + mr * 64 + (((ks * 4 + quad) ^ (mr & 7)) * 8));
        int nr = wn * 64 + t * 16 + l15;
        bfr[t] = *(const s16x8*)(Bs + nr * 64 + (((ks * 4 + quad) ^ (nr & 7)) * 8));
      }
#pragma unroll
      for (int tm = 0; tm < 4; tm++)
#pragma unroll
        for (int tn = 0; tn < 4; tn++)
          acc[tm][tn] = __builtin_amdgcn_mfma_f32_16x16x32_bf16(af[tm], bfr[tn], acc[tm][tn], 0, 0, 0);
    }
    __syncthreads();
  }

  // epilogue: C layout col=lane&15, row=quad*4+reg. Even lane packs (even,odd) cols -> u32 store.
  const bool ev = (lane & 1) == 0;
#pragma unroll
  for (int tm = 0; tm < 4; tm++) {
    int rowb = m0 + wm * 64 + tm * 16 + quad * 4;
#pragma unroll
    for (int tn = 0; tn < 4; tn++) {
      int col = n0 + wn * 64 + tn * 16 + l15;
      f32x4 v = acc[tm][tn];
      if (ROPE) {
        // inv_freq/(2pi), angle kept in revolutions, fract-reduced (v_sin range!)
        float invr = exp2f(-(float)(col & ~1) * (13.287712379549449f / 1024.0f)) * 0.15915494309f;
#pragma unroll
        for (int g = 0; g < 4; g++) {
          int row = rowb + g;
          float rev = (float)(row & (SQ - 1)) * invr;
          rev -= floorf(rev);
          float sn, cs;
          __sincosf(rev * 6.283185307179586f, &sn, &cs);
          float part = __shfl_xor(v[g], 1);
          float e = ev ? v[g] : part;
          float o = ev ? part : v[g];
          float re = e * cs - o * sn;
          float ro = e * sn + o * cs;
          if (ev) {
            unsigned int pk = (unsigned int)f2bf(re) | ((unsigned int)f2bf(ro) << 16);
            *(unsigned int*)(C + (size_t)row * DM + col) = pk;
          }
        }
      } else {
#pragma unroll
        for (int g = 0; g < 4; g++) {
          int row = rowb + g;
          float part = __shfl_xor(v[g], 1);
          if (ev) {
            unsigned int pk = (unsigned int)f2bf(v[g]) | ((unsigned int)f2bf(part) << 16);
            *(unsigned int*)(C + (size_t)row * DM + col) = pk;
          }
        }
      }
    }
  }
}

// ---------------- V [b][s][d] -> Vt [b][d][s] ----------------
__global__ __launch_bounds__(256)
void transpose_k(const unsigned short* __restrict__ V, unsigned short* __restrict__ Vt) {
  const int b = blockIdx.y;
  const int s0 = blockIdx.x * 64;
  const int lane = threadIdx.x & 63, w = threadIdx.x >> 6;
  const unsigned short* Vb = V + (size_t)b * SQ * DM;
  unsigned short* Vtb = Vt + (size_t)b * DM * SQ;
  const int s = s0 + lane;
#pragma unroll 4
  for (int i = 0; i < 32; i++) {
    int d = (w * 32 + i) * 8;
    int4 v = *(const int4*)(Vb + (size_t)s * DM + d);
    const unsigned short* pv = (const unsigned short*)&v;
#pragma unroll
    for (int j = 0; j < 8; j++)
      Vtb[(size_t)(d + j) * SQ + s] = pv[j];   // 64 lanes -> 128B coalesced per (i,j)
  }
}

// ---------------- flash attention, Br=Bc=32, causal, online softmax ----------------
#define QK_LD 1032   // 1024 + 8 pad (keeps ds_read_b128 16B-aligned, 2-way banks = free)
#define P_LD  40     // 32 + 8 pad

__global__ __launch_bounds__(256, 1)
void flash(const unsigned short* __restrict__ Q,
           const unsigned short* __restrict__ K,
           const unsigned short* __restrict__ Vt,
           float* __restrict__ O) {
  extern __shared__ unsigned short sm[];
  unsigned short* Qs = sm;                    // 32 x QK_LD
  unsigned short* Ks = Qs + 32 * QK_LD;       // 32 x QK_LD
  unsigned short* Ps = Ks + 32 * QK_LD;       // 32 x P_LD
  float* m_i  = (float*)(Ps + 32 * P_LD);     // [32]
  float* l_i  = m_i + 32;                     // [32]
  float* alph = m_i + 64;                     // [32]
  float* tmax = m_i + 96;                     // [2][32]
  float* tsum = m_i + 160;                    // [2][32]

  const int tid = threadIdx.x, lane = tid & 63, wid = tid >> 6;
  const int quad = lane >> 4, l15 = lane & 15;
  const int wr = wid >> 1, wc = wid & 1;
  const int b = blockIdx.y;
  const int qt = gridDim.x - 1 - blockIdx.x;  // longest q-tiles dispatched first
  const int q0 = qt * 32;
  const int d0 = wid * 256;                   // this wave's output d-slice

  const unsigned short* Qg = Q + ((size_t)b * SQ + q0) * DM;
  const unsigned short* Kg = K + (size_t)b * SQ * DM;
  const unsigned short* Vg = Vt + (size_t)b * DM * SQ;

  for (int c = tid; c < 4096; c += 256) {
    int r = c >> 7, col = (c & 127) * 8;
    *(int4*)(Qs + r * QK_LD + col) = *(const int4*)(Qg + (size_t)r * DM + col);
  }
  if (tid < 32) { m_i[tid] = -INFINITY; l_i[tid] = 0.f; }

  f32x4 zero = {0.f, 0.f, 0.f, 0.f};
  f32x4 oacc[2][16];
#pragma unroll
  for (int t = 0; t < 2; t++)
#pragma unroll
    for (int d = 0; d < 16; d++) oacc[t][d] = zero;

  __syncthreads();

  for (int kt = 0; kt <= qt; kt++) {
    const int k0 = kt * 32;
    for (int c = tid; c < 4096; c += 256) {
      int r = c >> 7, col = (c & 127) * 8;
      *(int4*)(Ks + r * QK_LD + col) = *(const int4*)(Kg + ((size_t)(k0 + r)) * DM + col);
    }
    __syncthreads();

    // ---- S = Q K^T : each wave one 16x16 tile over full D (4 indep acc chains) ----
    f32x4 sa0 = zero, sa1 = zero, sa2 = zero, sa3 = zero;
    const unsigned short* qb = Qs + (wr * 16 + l15) * QK_LD + quad * 8;
    const unsigned short* kb = Ks + (wc * 16 + l15) * QK_LD + quad * 8;
#pragma unroll
    for (int ks = 0; ks < 32; ks += 4) {
      sa0 = __builtin_amdgcn_mfma_f32_16x16x32_bf16(*(const s16x8*)(qb + (ks + 0) * 32), *(const s16x8*)(kb + (ks + 0) * 32), sa0, 0, 0, 0);
      sa1 = __builtin_amdgcn_mfma_f32_16x16x32_bf16(*(const s16x8*)(qb + (ks + 1) * 32), *(const s16x8*)(kb + (ks + 1) * 32), sa1, 0, 0, 0);
      sa2 = __builtin_amdgcn_mfma_f32_16x16x32_bf16(*(const s16x8*)(qb + (ks + 2) * 32), *(const s16x8*)(kb + (ks + 2) * 32), sa2, 0, 0, 0);
      sa3 = __builtin_amdgcn_mfma_f32_16x16x32_bf16(*(const s16x8*)(qb + (ks + 3) * 32), *(const s16x8*)(kb + (ks + 3) * 32), sa3, 0, 0, 0);
    }
    f32x4 sv4 = sa0 + sa1 + sa2 + sa3;

    // ---- scale, causal mask, tile row-max ----
    float sv[4], mx[4];
    const int colg = k0 + wc * 16 + l15;
    const int rowb = q0 + wr * 16 + quad * 4;
#pragma unroll
    for (int g = 0; g < 4; g++) {
      float x = sv4[g] * 0.03125f;
      if (colg > rowb + g) x = -INFINITY;
      sv[g] = x; mx[g] = x;
    }
#pragma unroll
    for (int off = 1; off < 16; off <<= 1)
#pragma unroll
      for (int g = 0; g < 4; g++) mx[g] = fmaxf(mx[g], __shfl_xor(mx[g], off));
    if (l15 == 0) {
#pragma unroll
      for (int g = 0; g < 4; g++) tmax[wc * 32 + wr * 16 + quad * 4 + g] = mx[g];
    }
    __syncthreads();
    if (tid < 32) {
      float mo = m_i[tid];
      float mn = fmaxf(mo, fmaxf(tmax[tid], tmax[32 + tid]));
      alph[tid] = __expf(mo - mn);
      m_i[tid] = mn;
    }
    __syncthreads();

    // ---- P = exp(S - m_new), write LDS (A-layout source), row sums ----
    float p[4], rs[4];
#pragma unroll
    for (int g = 0; g < 4; g++) {
      float mn = m_i[wr * 16 + quad * 4 + g];
      p[g] = __expf(sv[g] - mn);
      rs[g] = p[g];
      Ps[(wr * 16 + quad * 4 + g) * P_LD + wc * 16 + l15] = f2bf(p[g]);
    }
#pragma unroll
    for (int off = 1; off < 16; off <<= 1)
#pragma unroll
      for (int g = 0; g < 4; g++) rs[g] += __shfl_xor(rs[g], off);
    if (l15 == 0) {
#pragma unroll
      for (int g = 0; g < 4; g++) tsum[wc * 32 + wr * 16 + quad * 4 + g] = rs[g];
    }
    __syncthreads();
    if (tid < 32) l_i[tid] = l_i[tid] * alph[tid] + tsum[tid] + tsum[32 + tid];

    // ---- O = O*alpha + P @ V (V-fragments direct from global Vt, contiguous 16B) ----
    float al[2][4];
#pragma unroll
    for (int t = 0; t < 2; t++)
#pragma unroll
      for (int g = 0; g < 4; g++) al[t][g] = alph[t * 16 + quad * 4 + g];
#pragma unroll
    for (int t = 0; t < 2; t++)
#pragma unroll
      for (int d = 0; d < 16; d++)
#pragma unroll
        for (int g = 0; g < 4; g++) oacc[t][d][g] *= al[t][g];

    s16x8 ap0 = *(const s16x8*)(Ps + l15 * P_LD + quad * 8);
    s16x8 ap1 = *(const s16x8*)(Ps + (16 + l15) * P_LD + quad * 8);
    s16x8 bv[16];
#pragma unroll
    for (int d = 0; d < 16; d++)
      bv[d] = *(const s16x8*)(Vg + (size_t)(d0 + d * 16 + l15) * SQ + k0 + quad * 8);
#pragma unroll
    for (int d = 0; d < 16; d++) {
      oacc[0][d] = __builtin_amdgcn_mfma_f32_16x16x32_bf16(ap0, bv[d], oacc[0][d], 0, 0, 0);
      oacc[1][d] = __builtin_amdgcn_mfma_f32_16x16x32_bf16(ap1, bv[d], oacc[1][d], 0, 0, 0);
    }
    __syncthreads();
  }

  // ---- epilogue: O /= l ----
  float linv[2][4];
#pragma unroll
  for (int t = 0; t < 2; t++)
#pragma unroll
    for (int g = 0; g < 4; g++) linv[t][g] = 1.0f / l_i[t * 16 + quad * 4 + g];

  float* Ob = O + ((size_t)b * SQ + q0) * DM;
#pragma unroll
  for (int t = 0; t < 2; t++)
#pragma unroll
    for (int d = 0; d < 16; d++)
#pragma unroll
      for (int g = 0; g < 4; g++)
        Ob[(size_t)(t * 16 + quad * 4 + g) * DM + d0 + d * 16 + l15] = oacc[t][d][g] * linv[t][g];
}

#define FLASH_LDS ((2 * 32 * QK_LD + 32 * P_LD) * 2 + 224 * 4)

extern "C" void kernel_launch(void* const* d_in, const int* in_sizes, int n_in,
                              void* d_out, int out_size, void* d_ws, size_t ws_size,
                              hipStream_t stream) {
  const float* x  = (const float*)d_in[0];
  const float* Wq = (const float*)d_in[1];
  const float* Wk = (const float*)d_in[2];
  const float* Wv = (const float*)d_in[3];
  float* out = (float*)d_out;

  // workspace layout (bf16 elements); Vt aliases xb (xb dead after the 3 GEMMs)
  unsigned short* xb  = (unsigned short*)d_ws;
  unsigned short* Wqb = xb  + (size_t)MT * DM;
  unsigned short* Wkb = Wqb + (size_t)DM * DM;
  unsigned short* Wvb = Wkb + (size_t)DM * DM;
  unsigned short* Qb  = Wvb + (size_t)DM * DM;
  unsigned short* Kb  = Qb  + (size_t)MT * DM;
  unsigned short* Vb  = Kb  + (size_t)MT * DM;
  unsigned short* Vtb = xb;   // alias: transpose runs after all GEMMs

  cvt<<<MT * DM / 1024, 256, 0, stream>>>(x, xb);
  cvt<<<DM * DM / 1024, 256, 0, stream>>>(Wq, Wqb);
  cvt<<<DM * DM / 1024, 256, 0, stream>>>(Wk, Wkb);
  cvt<<<DM * DM / 1024, 256, 0, stream>>>(Wv, Wvb);

  dim3 gg(MT / 128, DM / 128);
  gemm_rope<1><<<gg, 256, 0, stream>>>(xb, Wqb, Qb);
  gemm_rope<1><<<gg, 256, 0, stream>>>(xb, Wkb, Kb);
  gemm_rope<0><<<gg, 256, 0, stream>>>(xb, Wvb, Vb);

  transpose_k<<<dim3(SQ / 64, NB), 256, 0, stream>>>(Vb, Vtb);

  (void)hipFuncSetAttribute((const void*)flash,
                            hipFuncAttributeMaxDynamicSharedMemorySize, FLASH_LDS);
  flash<<<dim3(SQ / 32, NB), 256, FLASH_LDS, stream>>>(Qb, Kb, Vtb, out);
}

// Round 2
// 629.771 us; speedup vs baseline: 3.3833x; 3.3833x over previous
//
#include <hip/hip_runtime.h>
#include <math.h>

#define SQ 4096
#define DM 1024
#define NB 4
#define MT (NB*SQ)   // 16384 flattened rows

typedef __attribute__((ext_vector_type(4))) float f32x4;
typedef __attribute__((ext_vector_type(8))) short s16x8;

__device__ __forceinline__ unsigned short f2bf(float f) {
  union { float f; unsigned int u; } v; v.f = f;
  unsigned int u = v.u;
  u += 0x7fffu + ((u >> 16) & 1u);   // RNE
  return (unsigned short)(u >> 16);
}

__device__ __forceinline__ float bf2f(unsigned short u) {
  union { unsigned int i; float f; } v; v.i = ((unsigned int)u) << 16;
  return v.f;
}

__device__ __forceinline__ void async16(const void* g, void* l) {
  __builtin_amdgcn_global_load_lds(
      (const __attribute__((address_space(1))) unsigned int*)g,
      (__attribute__((address_space(3))) unsigned int*)l, 16, 0, 0);
}

// ---------------- fp32 -> bf16 convert ----------------
__global__ __launch_bounds__(256)
void cvt(const float* __restrict__ in, unsigned short* __restrict__ out) {
  size_t i = ((size_t)blockIdx.x * 256 + threadIdx.x) * 4;
  float4 f = *(const float4*)(in + i);
  ushort4 o;
  o.x = f2bf(f.x); o.y = f2bf(f.y); o.z = f2bf(f.z); o.w = f2bf(f.w);
  *(ushort4*)(out + i) = o;
}

// ---------------- shared m97-style 128x128xBK64 K-loop ----------------
// A[m][k] row-major stride LDA, B[n][k] row-major stride LDB, bf16.
template<int LDA, int LDB>
__device__ __forceinline__ void gemm_tile_body(
    const unsigned short* __restrict__ A, const unsigned short* __restrict__ B,
    unsigned short* As, unsigned short* Bs,
    int m0, int n0, int kext, f32x4 acc[4][4]) {
  const int tid = threadIdx.x, lane = tid & 63, wid = tid >> 6;
  const int quad = lane >> 4, l15 = lane & 15;
  const int wm = wid & 1, wn = wid >> 1;
  for (int k0 = 0; k0 < kext; k0 += 64) {
#pragma unroll
    for (int c = 0; c < 4; c++) {
      int slot = (wid * 4 + c) * 64 + lane;
      int r = slot >> 3;
      int kg = (slot & 7) ^ (r & 7);
      async16(A + (size_t)(m0 + r) * LDA + k0 + kg * 8, As + slot * 8);
      async16(B + (size_t)(n0 + r) * LDB + k0 + kg * 8, Bs + slot * 8);
    }
    asm volatile("s_waitcnt vmcnt(0)" ::: "memory");
    __syncthreads();
#pragma unroll
    for (int ks = 0; ks < 2; ks++) {
      s16x8 af[4], bfr[4];
#pragma unroll
      for (int t = 0; t < 4; t++) {
        int mr = wm * 64 + t * 16 + l15;
        af[t]  = *(const s16x8*)(As + mr * 64 + (((ks * 4 + quad) ^ (mr & 7)) * 8));
        int nr = wn * 64 + t * 16 + l15;
        bfr[t] = *(const s16x8*)(Bs + nr * 64 + (((ks * 4 + quad) ^ (nr & 7)) * 8));
      }
#pragma unroll
      for (int tm = 0; tm < 4; tm++)
#pragma unroll
        for (int tn = 0; tn < 4; tn++)
          acc[tm][tn] = __builtin_amdgcn_mfma_f32_16x16x32_bf16(af[tm], bfr[tn], acc[tm][tn], 0, 0, 0);
    }
    __syncthreads();
  }
}

// ---------------- GEMM C = A * B^T (bf16 in/out), optional fused RoPE (round-1 proven) ----------------
template<int ROPE>
__global__ __launch_bounds__(256)
void gemm_rope(const unsigned short* __restrict__ A,
               const unsigned short* __restrict__ Bw,
               unsigned short* __restrict__ C) {
  __shared__ unsigned short As[128 * 64];
  __shared__ unsigned short Bs[128 * 64];
  const int tid = threadIdx.x, lane = tid & 63, wid = tid >> 6;
  const int quad = lane >> 4, l15 = lane & 15;
  const int wm = wid & 1, wn = wid >> 1;
  const int m0 = blockIdx.x * 128, n0 = blockIdx.y * 128;

  f32x4 zero = {0.f, 0.f, 0.f, 0.f};
  f32x4 acc[4][4];
#pragma unroll
  for (int i = 0; i < 4; i++)
#pragma unroll
    for (int j = 0; j < 4; j++) acc[i][j] = zero;

  gemm_tile_body<DM, DM>(A, Bw, As, Bs, m0, n0, DM, acc);

  const bool ev = (lane & 1) == 0;
#pragma unroll
  for (int tm = 0; tm < 4; tm++) {
    int rowb = m0 + wm * 64 + tm * 16 + quad * 4;
#pragma unroll
    for (int tn = 0; tn < 4; tn++) {
      int col = n0 + wn * 64 + tn * 16 + l15;
      f32x4 v = acc[tm][tn];
      if (ROPE) {
        float invr = exp2f(-(float)(col & ~1) * (13.287712379549449f / 1024.0f)) * 0.15915494309f;
#pragma unroll
        for (int g = 0; g < 4; g++) {
          int row = rowb + g;
          float rev = (float)(row & (SQ - 1)) * invr;
          rev -= floorf(rev);
          float sn, cs;
          __sincosf(rev * 6.283185307179586f, &sn, &cs);
          float part = __shfl_xor(v[g], 1);
          float e = ev ? v[g] : part;
          float o = ev ? part : v[g];
          float re = e * cs - o * sn;
          float ro = e * sn + o * cs;
          if (ev) {
            unsigned int pk = (unsigned int)f2bf(re) | ((unsigned int)f2bf(ro) << 16);
            *(unsigned int*)(C + (size_t)row * DM + col) = pk;
          }
        }
      } else {
#pragma unroll
        for (int g = 0; g < 4; g++) {
          int row = rowb + g;
          float part = __shfl_xor(v[g], 1);
          if (ev) {
            unsigned int pk = (unsigned int)f2bf(v[g]) | ((unsigned int)f2bf(part) << 16);
            *(unsigned int*)(C + (size_t)row * DM + col) = pk;
          }
        }
      }
    }
  }
}

// ---------------- V [b][s][d] -> Vt [b][d][s] ----------------
__global__ __launch_bounds__(256)
void transpose_k(const unsigned short* __restrict__ V, unsigned short* __restrict__ Vt) {
  const int b = blockIdx.y;
  const int s0 = blockIdx.x * 64;
  const int lane = threadIdx.x & 63, w = threadIdx.x >> 6;
  const unsigned short* Vb = V + (size_t)b * SQ * DM;
  unsigned short* Vtb = Vt + (size_t)b * DM * SQ;
  const int s = s0 + lane;
#pragma unroll 4
  for (int i = 0; i < 32; i++) {
    int d = (w * 32 + i) * 8;
    int4 v = *(const int4*)(Vb + (size_t)s * DM + d);
    const unsigned short* pv = (const unsigned short*)&v;
#pragma unroll
    for (int j = 0; j < 8; j++)
      Vtb[(size_t)(d + j) * SQ + s] = pv[j];
  }
}

// ---------------- pass1: S = Q K^T / 32, causal tiles only, bf16 out ----------------
// grid.x = 528 linear causal tile id (nt<=mt of 32x32 tiles), grid.y = batch-in-group
__global__ __launch_bounds__(256)
void qk_gemm(const unsigned short* __restrict__ Q, const unsigned short* __restrict__ K,
             unsigned short* __restrict__ S) {
  __shared__ unsigned short As[128 * 64];
  __shared__ unsigned short Bs[128 * 64];
  const int lane = threadIdx.x & 63, wid = threadIdx.x >> 6;
  const int quad = lane >> 4, l15 = lane & 15;
  const int wm = wid & 1, wn = wid >> 1;

  int t = blockIdx.x;
  int mt = (int)((sqrtf(8.f * (float)t + 1.f) - 1.f) * 0.5f);
  while ((mt + 1) * (mt + 2) / 2 <= t) ++mt;
  while (mt * (mt + 1) / 2 > t) --mt;
  int nt = t - mt * (mt + 1) / 2;

  const unsigned short* Qg = Q + (size_t)blockIdx.y * SQ * DM;
  const unsigned short* Kg = K + (size_t)blockIdx.y * SQ * DM;
  unsigned short* Sg = S + (size_t)blockIdx.y * SQ * SQ;

  f32x4 zero = {0.f, 0.f, 0.f, 0.f};
  f32x4 acc[4][4];
#pragma unroll
  for (int i = 0; i < 4; i++)
#pragma unroll
    for (int j = 0; j < 4; j++) acc[i][j] = zero;

  gemm_tile_body<DM, DM>(Qg, Kg, As, Bs, mt * 128, nt * 128, DM, acc);

  const bool ev = (lane & 1) == 0;
#pragma unroll
  for (int tm = 0; tm < 4; tm++) {
    int rowb = mt * 128 + wm * 64 + tm * 16 + quad * 4;
#pragma unroll
    for (int tn = 0; tn < 4; tn++) {
      int col = nt * 128 + wn * 64 + tn * 16 + l15;
      f32x4 v = acc[tm][tn];
#pragma unroll
      for (int g = 0; g < 4; g++) {
        float sv = v[g] * 0.03125f;
        float part = __shfl_xor(sv, 1);
        if (ev) {
          unsigned int pk = (unsigned int)f2bf(sv) | ((unsigned int)f2bf(part) << 16);
          *(unsigned int*)(Sg + (size_t)(rowb + g) * SQ + col) = pk;
        }
      }
    }
  }
}

// ---------------- pass2: per-row softmax in place (bf16), store 1/l ----------------
// grid.x = row (0..4095), grid.y = batch-in-group. Zero-pads the diagonal tile.
__global__ __launch_bounds__(256)
void softmax_row(unsigned short* __restrict__ S, float* __restrict__ linv) {
  __shared__ int4 rowbuf4[512];   // 8 KB: entire row bf16
  __shared__ float redm[4], reds[4];
  unsigned short* rowbuf = (unsigned short*)rowbuf4;
  const int tid = threadIdx.x, lane = tid & 63, wid = tid >> 6;
  const int row = blockIdx.x;
  unsigned short* Srow = S + (size_t)blockIdx.y * SQ * SQ + (size_t)row * SQ;
  float* lg = linv + blockIdx.y * SQ;
  const int L = row + 1;
  const int nch = (L + 7) >> 3;                    // chunks holding causal data
  const int pch = ((((row >> 7) + 1) << 7)) >> 3;  // chunks to 128-aligned pad end

  float lmax = -INFINITY;
  for (int c = tid; c < nch; c += 256) {
    int4 v = *(const int4*)(Srow + (size_t)c * 8);
    rowbuf4[c] = v;
    const unsigned short* pe = (const unsigned short*)&v;
#pragma unroll
    for (int j = 0; j < 8; j++)
      if (c * 8 + j < L) lmax = fmaxf(lmax, bf2f(pe[j]));
  }
#pragma unroll
  for (int o = 32; o >= 1; o >>= 1) lmax = fmaxf(lmax, __shfl_xor(lmax, o));
  if (lane == 0) redm[wid] = lmax;
  __syncthreads();
  const float m = fmaxf(fmaxf(redm[0], redm[1]), fmaxf(redm[2], redm[3]));

  float lsum = 0.f;
  for (int c = tid; c < pch; c += 256) {
    union { int4 v; unsigned short s[8]; } o;
    if (c < nch) {
      const unsigned short* pe = rowbuf + c * 8;
#pragma unroll
      for (int j = 0; j < 8; j++) {
        float p = (c * 8 + j < L) ? __expf(bf2f(pe[j]) - m) : 0.f;
        lsum += p;
        o.s[j] = f2bf(p);
      }
    } else {
#pragma unroll
      for (int j = 0; j < 8; j++) o.s[j] = 0;
    }
    *(int4*)(Srow + (size_t)c * 8) = o.v;
  }
#pragma unroll
  for (int o = 32; o >= 1; o >>= 1) lsum += __shfl_xor(lsum, o);
  if (lane == 0) reds[wid] = lsum;
  __syncthreads();
  if (tid == 0) lg[row] = 1.0f / (reds[0] + reds[1] + reds[2] + reds[3]);
}

// ---------------- pass3: O = P @ V (Vt layout), scale 1/l, fp32 out ----------------
// grid.x = 256: mt = 31 - (bx>>3) (longest-K first), nt = bx&7. grid.y = batch-in-group.
__global__ __launch_bounds__(256)
void pv_gemm(const unsigned short* __restrict__ P, const unsigned short* __restrict__ Vt,
             const float* __restrict__ linv, float* __restrict__ O) {
  __shared__ unsigned short As[128 * 64];
  __shared__ unsigned short Bs[128 * 64];
  const int lane = threadIdx.x & 63, wid = threadIdx.x >> 6;
  const int quad = lane >> 4, l15 = lane & 15;
  const int wm = wid & 1, wn = wid >> 1;

  const int mt = 31 - (blockIdx.x >> 3);
  const int nt = blockIdx.x & 7;

  const unsigned short* Pg = P + (size_t)blockIdx.y * SQ * SQ;
  const unsigned short* Vg = Vt + (size_t)blockIdx.y * DM * SQ;
  const float* lg = linv + blockIdx.y * SQ;
  float* Og = O + (size_t)blockIdx.y * SQ * DM;

  f32x4 zero = {0.f, 0.f, 0.f, 0.f};
  f32x4 acc[4][4];
#pragma unroll
  for (int i = 0; i < 4; i++)
#pragma unroll
    for (int j = 0; j < 4; j++) acc[i][j] = zero;

  gemm_tile_body<SQ, SQ>(Pg, Vg, As, Bs, mt * 128, nt * 128, (mt + 1) * 128, acc);

  const bool ev = (lane & 1) == 0;
#pragma unroll
  for (int tm = 0; tm < 4; tm++) {
    int rowb = mt * 128 + wm * 64 + tm * 16 + quad * 4;
#pragma unroll
    for (int tn = 0; tn < 4; tn++) {
      int col = nt * 128 + wn * 64 + tn * 16 + l15;
      f32x4 v = acc[tm][tn];
#pragma unroll
      for (int g = 0; g < 4; g++) {
        float val = v[g] * lg[rowb + g];
        float part = __shfl_xor(val, 1);
        if (ev) {
          float2 st; st.x = val; st.y = part;
          *(float2*)(Og + (size_t)(rowb + g) * DM + col) = st;
        }
      }
    }
  }
}

extern "C" void kernel_launch(void* const* d_in, const int* in_sizes, int n_in,
                              void* d_out, int out_size, void* d_ws, size_t ws_size,
                              hipStream_t stream) {
  const float* x  = (const float*)d_in[0];
  const float* Wq = (const float*)d_in[1];
  const float* Wk = (const float*)d_in[2];
  const float* Wv = (const float*)d_in[3];
  float* out = (float*)d_out;

  // workspace layout (bf16 elems unless noted); Vt aliases xb (dead after GEMMs)
  unsigned short* xb  = (unsigned short*)d_ws;
  unsigned short* Wqb = xb  + (size_t)MT * DM;
  unsigned short* Wkb = Wqb + (size_t)DM * DM;
  unsigned short* Wvb = Wkb + (size_t)DM * DM;
  unsigned short* Qb  = Wvb + (size_t)DM * DM;
  unsigned short* Kb  = Qb  + (size_t)MT * DM;
  unsigned short* Vb  = Kb  + (size_t)MT * DM;
  unsigned short* Sb  = Vb  + (size_t)MT * DM;          // 2 batches of S/P: 2*SQ*SQ bf16
  float*          linv = (float*)(Sb + (size_t)2 * SQ * SQ);  // 2*SQ fp32
  unsigned short* Vtb = xb;   // alias

  cvt<<<MT * DM / 1024, 256, 0, stream>>>(x, xb);
  cvt<<<DM * DM / 1024, 256, 0, stream>>>(Wq, Wqb);
  cvt<<<DM * DM / 1024, 256, 0, stream>>>(Wk, Wkb);
  cvt<<<DM * DM / 1024, 256, 0, stream>>>(Wv, Wvb);

  dim3 gg(MT / 128, DM / 128);
  gemm_rope<1><<<gg, 256, 0, stream>>>(xb, Wqb, Qb);
  gemm_rope<1><<<gg, 256, 0, stream>>>(xb, Wkb, Kb);
  gemm_rope<0><<<gg, 256, 0, stream>>>(xb, Wvb, Vb);

  transpose_k<<<dim3(SQ / 64, NB), 256, 0, stream>>>(Vb, Vtb);

  // attention in 2 groups of 2 batches (S buffer holds 2 batches)
  for (int g = 0; g < 2; ++g) {
    qk_gemm<<<dim3(528, 2), 256, 0, stream>>>(
        Qb + (size_t)g * 2 * SQ * DM, Kb + (size_t)g * 2 * SQ * DM, Sb);
    softmax_row<<<dim3(SQ, 2), 256, 0, stream>>>(Sb, linv);
    pv_gemm<<<dim3(256, 2), 256, 0, stream>>>(
        Sb, Vtb + (size_t)g * 2 * DM * SQ, linv, out + (size_t)g * 2 * SQ * DM);
  }
}

// Round 3
// 612.581 us; speedup vs baseline: 3.4783x; 1.0281x over previous
//
#include <hip/hip_runtime.h>
#include <math.h>

#define SQ 4096
#define DM 1024
#define NB 4
#define MT (NB*SQ)   // 16384 flattened rows

typedef __attribute__((ext_vector_type(4))) float f32x4;
typedef __attribute__((ext_vector_type(8))) short s16x8;

__device__ __forceinline__ unsigned short f2bf(float f) {
  union { float f; unsigned int u; } v; v.f = f;
  unsigned int u = v.u;
  u += 0x7fffu + ((u >> 16) & 1u);   // RNE
  return (unsigned short)(u >> 16);
}

__device__ __forceinline__ float bf2f(unsigned short u) {
  union { unsigned int i; float f; } v; v.i = ((unsigned int)u) << 16;
  return v.f;
}

__device__ __forceinline__ void async16(const void* g, void* l) {
  __builtin_amdgcn_global_load_lds(
      (const __attribute__((address_space(1))) unsigned int*)g,
      (__attribute__((address_space(3))) unsigned int*)l, 16, 0, 0);
}

// ---------------- fp32 -> bf16 convert ----------------
__global__ __launch_bounds__(256)
void cvt(const float* __restrict__ in, unsigned short* __restrict__ out) {
  size_t i = ((size_t)blockIdx.x * 256 + threadIdx.x) * 4;
  float4 f = *(const float4*)(in + i);
  ushort4 o;
  o.x = f2bf(f.x); o.y = f2bf(f.y); o.z = f2bf(f.z); o.w = f2bf(f.w);
  *(ushort4*)(out + i) = o;
}

// ---------------- shared m97-style 128x128xBK64 K-loop ----------------
// A[m][k] row-major stride LDA, B[n][k] row-major stride LDB, bf16.
template<int LDA, int LDB>
__device__ __forceinline__ void gemm_tile_body(
    const unsigned short* __restrict__ A, const unsigned short* __restrict__ B,
    unsigned short* As, unsigned short* Bs,
    int m0, int n0, int kext, f32x4 acc[4][4]) {
  const int tid = threadIdx.x, lane = tid & 63, wid = tid >> 6;
  const int quad = lane >> 4, l15 = lane & 15;
  const int wm = wid & 1, wn = wid >> 1;
  for (int k0 = 0; k0 < kext; k0 += 64) {
#pragma unroll
    for (int c = 0; c < 4; c++) {
      int slot = (wid * 4 + c) * 64 + lane;
      int r = slot >> 3;
      int kg = (slot & 7) ^ (r & 7);
      async16(A + (size_t)(m0 + r) * LDA + k0 + kg * 8, As + slot * 8);
      async16(B + (size_t)(n0 + r) * LDB + k0 + kg * 8, Bs + slot * 8);
    }
    asm volatile("s_waitcnt vmcnt(0)" ::: "memory");
    __syncthreads();
#pragma unroll
    for (int ks = 0; ks < 2; ks++) {
      s16x8 af[4], bfr[4];
#pragma unroll
      for (int t = 0; t < 4; t++) {
        int mr = wm * 64 + t * 16 + l15;
        af[t]  = *(const s16x8*)(As + mr * 64 + (((ks * 4 + quad) ^ (mr & 7)) * 8));
        int nr = wn * 64 + t * 16 + l15;
        bfr[t] = *(const s16x8*)(Bs + nr * 64 + (((ks * 4 + quad) ^ (nr & 7)) * 8));
      }
#pragma unroll
      for (int tm = 0; tm < 4; tm++)
#pragma unroll
        for (int tn = 0; tn < 4; tn++)
          acc[tm][tn] = __builtin_amdgcn_mfma_f32_16x16x32_bf16(af[tm], bfr[tn], acc[tm][tn], 0, 0, 0);
    }
    __syncthreads();
  }
}

// ---------------- merged QKV projection GEMM, fused RoPE on Q/K ----------------
// A = x [MT][1024]; Wb = [3][1024][1024] (Q,K,V); out QKV = [3][MT][1024], all bf16.
// grid (MT/128, 24): by>>3 selects matrix, by&7 the 128-col slab.
__global__ __launch_bounds__(256)
void qkv_gemm(const unsigned short* __restrict__ A,
              const unsigned short* __restrict__ Wb,
              unsigned short* __restrict__ QKV) {
  __shared__ unsigned short As[128 * 64];
  __shared__ unsigned short Bs[128 * 64];
  const int tid = threadIdx.x, lane = tid & 63, wid = tid >> 6;
  const int quad = lane >> 4, l15 = lane & 15;
  const int wm = wid & 1, wn = wid >> 1;
  const int mat = blockIdx.y >> 3;
  const int m0 = blockIdx.x * 128, n0 = (blockIdx.y & 7) * 128;
  const bool rope = (mat < 2);

  const unsigned short* Bg = Wb + (size_t)mat * DM * DM;
  unsigned short* C = QKV + (size_t)mat * MT * DM;

  f32x4 zero = {0.f, 0.f, 0.f, 0.f};
  f32x4 acc[4][4];
#pragma unroll
  for (int i = 0; i < 4; i++)
#pragma unroll
    for (int j = 0; j < 4; j++) acc[i][j] = zero;

  gemm_tile_body<DM, DM>(A, Bg, As, Bs, m0, n0, DM, acc);

  const bool ev = (lane & 1) == 0;
#pragma unroll
  for (int tm = 0; tm < 4; tm++) {
    int rowb = m0 + wm * 64 + tm * 16 + quad * 4;
#pragma unroll
    for (int tn = 0; tn < 4; tn++) {
      int col = n0 + wn * 64 + tn * 16 + l15;
      f32x4 v = acc[tm][tn];
      if (rope) {
        // inv_freq/(2pi); angle in revolutions, fract-reduced (v_sin range)
        float invr = exp2f(-(float)(col & ~1) * (13.287712379549449f / 1024.0f)) * 0.15915494309f;
#pragma unroll
        for (int g = 0; g < 4; g++) {
          int row = rowb + g;
          float rev = (float)(row & (SQ - 1)) * invr;
          rev -= floorf(rev);
          float sn, cs;
          __sincosf(rev * 6.283185307179586f, &sn, &cs);
          float part = __shfl_xor(v[g], 1);
          float e = ev ? v[g] : part;
          float o = ev ? part : v[g];
          float re = e * cs - o * sn;
          float ro = e * sn + o * cs;
          if (ev) {
            unsigned int pk = (unsigned int)f2bf(re) | ((unsigned int)f2bf(ro) << 16);
            *(unsigned int*)(C + (size_t)row * DM + col) = pk;
          }
        }
      } else {
#pragma unroll
        for (int g = 0; g < 4; g++) {
          int row = rowb + g;
          float part = __shfl_xor(v[g], 1);
          if (ev) {
            unsigned int pk = (unsigned int)f2bf(v[g]) | ((unsigned int)f2bf(part) << 16);
            *(unsigned int*)(C + (size_t)row * DM + col) = pk;
          }
        }
      }
    }
  }
}

// ---------------- V [b][s][d] -> Vt [b][d][s] ----------------
__global__ __launch_bounds__(256)
void transpose_k(const unsigned short* __restrict__ V, unsigned short* __restrict__ Vt) {
  const int b = blockIdx.y;
  const int s0 = blockIdx.x * 64;
  const int lane = threadIdx.x & 63, w = threadIdx.x >> 6;
  const unsigned short* Vb = V + (size_t)b * SQ * DM;
  unsigned short* Vtb = Vt + (size_t)b * DM * SQ;
  const int s = s0 + lane;
#pragma unroll 4
  for (int i = 0; i < 32; i++) {
    int d = (w * 32 + i) * 8;
    int4 v = *(const int4*)(Vb + (size_t)s * DM + d);
    const unsigned short* pv = (const unsigned short*)&v;
#pragma unroll
    for (int j = 0; j < 8; j++)
      Vtb[(size_t)(d + j) * SQ + s] = pv[j];
  }
}

// ---------------- pass1: S = Q K^T / 32, causal tiles only, bf16 out ----------------
// 1-D grid of 528*G blocks: b = bx % G, t = bx / G (triangular tile id, nt<=mt).
__global__ __launch_bounds__(256)
void qk_gemm(const unsigned short* __restrict__ Q, const unsigned short* __restrict__ K,
             unsigned short* __restrict__ S, int G) {
  __shared__ unsigned short As[128 * 64];
  __shared__ unsigned short Bs[128 * 64];
  const int lane = threadIdx.x & 63, wid = threadIdx.x >> 6;
  const int quad = lane >> 4, l15 = lane & 15;
  const int wm = wid & 1, wn = wid >> 1;

  const int b = blockIdx.x % G;
  int t = blockIdx.x / G;
  int mt = (int)((sqrtf(8.f * (float)t + 1.f) - 1.f) * 0.5f);
  while ((mt + 1) * (mt + 2) / 2 <= t) ++mt;
  while (mt * (mt + 1) / 2 > t) --mt;
  int nt = t - mt * (mt + 1) / 2;

  const unsigned short* Qg = Q + (size_t)b * SQ * DM;
  const unsigned short* Kg = K + (size_t)b * SQ * DM;
  unsigned short* Sg = S + (size_t)b * SQ * SQ;

  f32x4 zero = {0.f, 0.f, 0.f, 0.f};
  f32x4 acc[4][4];
#pragma unroll
  for (int i = 0; i < 4; i++)
#pragma unroll
    for (int j = 0; j < 4; j++) acc[i][j] = zero;

  gemm_tile_body<DM, DM>(Qg, Kg, As, Bs, mt * 128, nt * 128, DM, acc);

  const bool ev = (lane & 1) == 0;
#pragma unroll
  for (int tm = 0; tm < 4; tm++) {
    int rowb = mt * 128 + wm * 64 + tm * 16 + quad * 4;
#pragma unroll
    for (int tn = 0; tn < 4; tn++) {
      int col = nt * 128 + wn * 64 + tn * 16 + l15;
      f32x4 v = acc[tm][tn];
#pragma unroll
      for (int g = 0; g < 4; g++) {
        float sv = v[g] * 0.03125f;
        float part = __shfl_xor(sv, 1);
        if (ev) {
          unsigned int pk = (unsigned int)f2bf(sv) | ((unsigned int)f2bf(part) << 16);
          *(unsigned int*)(Sg + (size_t)(rowb + g) * SQ + col) = pk;
        }
      }
    }
  }
}

// ---------------- pass2: per-row softmax in place (bf16), store 1/l ----------------
__global__ __launch_bounds__(256)
void softmax_row(unsigned short* __restrict__ S, float* __restrict__ linv) {
  __shared__ int4 rowbuf4[512];   // 8 KB: entire row bf16
  __shared__ float redm[4], reds[4];
  unsigned short* rowbuf = (unsigned short*)rowbuf4;
  const int tid = threadIdx.x, lane = tid & 63, wid = tid >> 6;
  const int row = blockIdx.x;
  unsigned short* Srow = S + (size_t)blockIdx.y * SQ * SQ + (size_t)row * SQ;
  float* lg = linv + blockIdx.y * SQ;
  const int L = row + 1;
  const int nch = (L + 7) >> 3;                    // chunks holding causal data
  const int pch = ((((row >> 7) + 1) << 7)) >> 3;  // chunks to 128-aligned pad end

  float lmax = -INFINITY;
  for (int c = tid; c < nch; c += 256) {
    int4 v = *(const int4*)(Srow + (size_t)c * 8);
    rowbuf4[c] = v;
    const unsigned short* pe = (const unsigned short*)&v;
#pragma unroll
    for (int j = 0; j < 8; j++)
      if (c * 8 + j < L) lmax = fmaxf(lmax, bf2f(pe[j]));
  }
#pragma unroll
  for (int o = 32; o >= 1; o >>= 1) lmax = fmaxf(lmax, __shfl_xor(lmax, o));
  if (lane == 0) redm[wid] = lmax;
  __syncthreads();
  const float m = fmaxf(fmaxf(redm[0], redm[1]), fmaxf(redm[2], redm[3]));

  float lsum = 0.f;
  for (int c = tid; c < pch; c += 256) {
    union { int4 v; unsigned short s[8]; } o;
    if (c < nch) {
      const unsigned short* pe = rowbuf + c * 8;
#pragma unroll
      for (int j = 0; j < 8; j++) {
        float p = (c * 8 + j < L) ? __expf(bf2f(pe[j]) - m) : 0.f;
        lsum += p;
        o.s[j] = f2bf(p);
      }
    } else {
#pragma unroll
      for (int j = 0; j < 8; j++) o.s[j] = 0;
    }
    *(int4*)(Srow + (size_t)c * 8) = o.v;
  }
#pragma unroll
  for (int o = 32; o >= 1; o >>= 1) lsum += __shfl_xor(lsum, o);
  if (lane == 0) reds[wid] = lsum;
  __syncthreads();
  if (tid == 0) lg[row] = 1.0f / (reds[0] + reds[1] + reds[2] + reds[3]);
}

// ---------------- pass3: O = P @ V (Vt layout), scale 1/l, fp32 out ----------------
// 1-D grid of 256*G blocks: b = bx % G, t = bx / G; mt = 31-(t>>3) (longest-K first
// across ALL batches simultaneously), nt = t&7.
__global__ __launch_bounds__(256)
void pv_gemm(const unsigned short* __restrict__ P, const unsigned short* __restrict__ Vt,
             const float* __restrict__ linv, float* __restrict__ O, int G) {
  __shared__ unsigned short As[128 * 64];
  __shared__ unsigned short Bs[128 * 64];
  const int lane = threadIdx.x & 63, wid = threadIdx.x >> 6;
  const int quad = lane >> 4, l15 = lane & 15;
  const int wm = wid & 1, wn = wid >> 1;

  const int b = blockIdx.x % G;
  const int t = blockIdx.x / G;
  const int mt = 31 - (t >> 3);
  const int nt = t & 7;

  const unsigned short* Pg = P + (size_t)b * SQ * SQ;
  const unsigned short* Vg = Vt + (size_t)b * DM * SQ;
  const float* lg = linv + b * SQ;
  float* Og = O + (size_t)b * SQ * DM;

  f32x4 zero = {0.f, 0.f, 0.f, 0.f};
  f32x4 acc[4][4];
#pragma unroll
  for (int i = 0; i < 4; i++)
#pragma unroll
    for (int j = 0; j < 4; j++) acc[i][j] = zero;

  gemm_tile_body<SQ, SQ>(Pg, Vg, As, Bs, mt * 128, nt * 128, (mt + 1) * 128, acc);

  const bool ev = (lane & 1) == 0;
#pragma unroll
  for (int tm = 0; tm < 4; tm++) {
    int rowb = mt * 128 + wm * 64 + tm * 16 + quad * 4;
#pragma unroll
    for (int tn = 0; tn < 4; tn++) {
      int col = nt * 128 + wn * 64 + tn * 16 + l15;
      f32x4 v = acc[tm][tn];
#pragma unroll
      for (int g = 0; g < 4; g++) {
        float val = v[g] * lg[rowb + g];
        float part = __shfl_xor(val, 1);
        if (ev) {
          float2 st; st.x = val; st.y = part;
          *(float2*)(Og + (size_t)(rowb + g) * DM + col) = st;
        }
      }
    }
  }
}

extern "C" void kernel_launch(void* const* d_in, const int* in_sizes, int n_in,
                              void* d_out, int out_size, void* d_ws, size_t ws_size,
                              hipStream_t stream) {
  const float* x  = (const float*)d_in[0];
  const float* Wq = (const float*)d_in[1];
  const float* Wk = (const float*)d_in[2];
  const float* Wv = (const float*)d_in[3];
  float* out = (float*)d_out;

  // workspace layout (bf16 elems unless noted); Vt aliases xb (dead after qkv_gemm)
  unsigned short* xb  = (unsigned short*)d_ws;
  unsigned short* Wb  = xb + (size_t)MT * DM;            // [3][DM][DM]
  unsigned short* Qb  = Wb + (size_t)3 * DM * DM;        // [3][MT][DM] = Q,K,V
  unsigned short* Kb  = Qb + (size_t)MT * DM;
  unsigned short* Vb  = Kb + (size_t)MT * DM;
  unsigned short* Sb  = Vb + (size_t)MT * DM;            // G batches of S/P
  unsigned short* Vtb = xb;   // alias

  // choose largest batch group that fits the workspace (ws_size is constant
  // across calls -> same launches every call, graph-capture safe)
  const size_t base_bytes = ((size_t)MT * DM + 3 * (size_t)DM * DM + 3 * (size_t)MT * DM) * 2;
  int G = 1;
  for (int g = 4; g >= 1; g >>= 1) {
    size_t need = base_bytes + (size_t)g * SQ * SQ * 2 + (size_t)g * SQ * 4;
    if (ws_size >= need) { G = g; break; }
  }
  float* linv = (float*)(Sb + (size_t)G * SQ * SQ);

  cvt<<<MT * DM / 1024, 256, 0, stream>>>(x, xb);
  cvt<<<DM * DM / 1024, 256, 0, stream>>>(Wq, Wb);
  cvt<<<DM * DM / 1024, 256, 0, stream>>>(Wk, Wb + (size_t)DM * DM);
  cvt<<<DM * DM / 1024, 256, 0, stream>>>(Wv, Wb + (size_t)2 * DM * DM);

  qkv_gemm<<<dim3(MT / 128, 24), 256, 0, stream>>>(xb, Wb, Qb);

  transpose_k<<<dim3(SQ / 64, NB), 256, 0, stream>>>(Vb, Vtb);

  for (int g = 0; g < NB; g += G) {
    qk_gemm<<<528 * G, 256, 0, stream>>>(
        Qb + (size_t)g * SQ * DM, Kb + (size_t)g * SQ * DM, Sb, G);
    softmax_row<<<dim3(SQ, G), 256, 0, stream>>>(Sb, linv);
    pv_gemm<<<256 * G, 256, 0, stream>>>(
        Sb, Vtb + (size_t)g * DM * SQ, linv, out + (size_t)g * SQ * DM, G);
  }
}